// Round 1
// baseline (280.261 us; speedup 1.0000x reference)
//
#include <hip/hip_runtime.h>
#include <math.h>

// MelGaussianFilteredMSE:
//   diff = 10^(mo/10) - 10^(tg/10)            (B=32, F=1025, T=2000, fp32)
//   out  = mean( (M @ diff along F)^2 )       M is BANDED: half-width <= 10
//
// Strategy: tile (b, t-tile, f-chunk). Stage diff (computed once per element)
// in LDS with a 10-row halo; stage the 21-wide band of M in LDS; each thread
// does a sliding-window 21-tap FIR over 5 rows x 8 cols, squares, accumulates.
// Deterministic 2-pass reduction through d_ws (no float atomics).

#define B_N 32
#define F_N 1025
#define T_N 2000

#define TT    128   // t-tile width (floats); 2000 % 4 == 0 so float4 loads never straddle the edge
#define FC    80    // output f-rows per chunk
#define LROWS 100   // FC + 2*10 halo
#define SDS   132   // padded LDS row stride in floats (16B aligned; balances banks across rb groups)
#define NT    256   // threads per block

#define LOG2_10_DIV10 0.33219280948873623f   // log2(10)/10 : 10^(x/10) = 2^(x*this)

__global__ __launch_bounds__(NT, 2)
void mel_mse_main(const float* __restrict__ mo_g, const float* __restrict__ tg_g,
                  const float* __restrict__ M, float* __restrict__ partials) {
    __shared__ float sd[LROWS * SDS];  // 100*132*4 = 52800 B
    __shared__ float sm[FC * 21];      // 80*21*4   =  6720 B
    __shared__ float red[NT];          //             1024 B   -> 60544 B total

    const int tid  = threadIdx.x;
    const int t0   = blockIdx.x * TT;
    const int f0   = blockIdx.y * FC;
    const int b    = blockIdx.z;
    const int base = f0 - 10;          // global row of LDS row 0

    // ---- phase 1a: band coefficients for this chunk's output rows ----
    for (int i = tid; i < FC * 21; i += NT) {
        const int f = f0 + i / 21;
        const int k = f - 10 + (i % 21);
        float v = 0.0f;
        if (f < F_N && k >= 0 && k < F_N) v = M[f * F_N + k];
        sm[i] = v;
    }

    // ---- phase 1b: diff tile -> LDS (zero-filled OOB so no masking later) ----
    for (int i = tid; i < LROWS * (TT / 4); i += NT) {
        const int r   = i >> 5;          // 32 float4 per row
        const int c4  = (i & 31) << 2;
        const int g   = base + r;
        const int col = t0 + c4;
        float4 v = make_float4(0.f, 0.f, 0.f, 0.f);
        if (g >= 0 && g < F_N && col < T_N) {
            const size_t off = ((size_t)b * F_N + g) * (size_t)T_N + col;
            const float4 a = *reinterpret_cast<const float4*>(mo_g + off);
            const float4 c = *reinterpret_cast<const float4*>(tg_g + off);
            v.x = exp2f(a.x * LOG2_10_DIV10) - exp2f(c.x * LOG2_10_DIV10);
            v.y = exp2f(a.y * LOG2_10_DIV10) - exp2f(c.y * LOG2_10_DIV10);
            v.z = exp2f(a.z * LOG2_10_DIV10) - exp2f(c.z * LOG2_10_DIV10);
            v.w = exp2f(a.w * LOG2_10_DIV10) - exp2f(c.w * LOG2_10_DIV10);
        }
        *reinterpret_cast<float4*>(&sd[r * SDS + c4]) = v;
    }
    __syncthreads();

    // ---- phase 2: banded matvec + square-accumulate ----
    // thread -> 8 cols (2 float4) x 5 consecutive output rows
    const int cg  = tid & 15;           // 16 col-groups * 8 cols = 128
    const int rb  = tid >> 4;           // 16 row-blocks * 5 rows = 80
    const int c0  = cg << 3;
    const int fl0 = rb * 5;             // local output-row base (0..75)

    float acc[5][8];
#pragma unroll
    for (int r = 0; r < 5; ++r)
#pragma unroll
        for (int c = 0; c < 8; ++c) acc[r][c] = 0.f;

    // k = f0 + fl0 - 10 + j  ->  LDS row = fl0 + j  (0..99, always in range)
#pragma unroll
    for (int j = 0; j < 25; ++j) {
        const int lr = fl0 + j;
        const float4 d0 = *reinterpret_cast<const float4*>(&sd[lr * SDS + c0]);
        const float4 d1 = *reinterpret_cast<const float4*>(&sd[lr * SDS + c0 + 4]);
#pragma unroll
        for (int r = 0; r < 5; ++r) {
            const int jj = j - r;                 // tap index, compile-time after unroll
            if (jj >= 0 && jj < 21) {
                const float m = sm[(fl0 + r) * 21 + jj];
                acc[r][0] = fmaf(m, d0.x, acc[r][0]);
                acc[r][1] = fmaf(m, d0.y, acc[r][1]);
                acc[r][2] = fmaf(m, d0.z, acc[r][2]);
                acc[r][3] = fmaf(m, d0.w, acc[r][3]);
                acc[r][4] = fmaf(m, d1.x, acc[r][4]);
                acc[r][5] = fmaf(m, d1.y, acc[r][5]);
                acc[r][6] = fmaf(m, d1.z, acc[r][6]);
                acc[r][7] = fmaf(m, d1.w, acc[r][7]);
            }
        }
    }

    float local = 0.f;
#pragma unroll
    for (int r = 0; r < 5; ++r)
#pragma unroll
        for (int c = 0; c < 8; ++c) local = fmaf(acc[r][c], acc[r][c], local);

    red[tid] = local;
    __syncthreads();
    for (int s = NT / 2; s > 0; s >>= 1) {
        if (tid < s) red[tid] += red[tid + s];
        __syncthreads();
    }
    if (tid == 0) {
        const int bid = blockIdx.x + gridDim.x * (blockIdx.y + gridDim.y * blockIdx.z);
        partials[bid] = red[0];
    }
}

__global__ void mel_mse_reduce(const float* __restrict__ partials, int n,
                               float* __restrict__ out) {
    __shared__ double red[256];
    double s = 0.0;
    for (int i = threadIdx.x; i < n; i += 256) s += (double)partials[i];
    red[threadIdx.x] = s;
    __syncthreads();
    for (int st = 128; st > 0; st >>= 1) {
        if (threadIdx.x < st) red[threadIdx.x] += red[threadIdx.x + st];
        __syncthreads();
    }
    if (threadIdx.x == 0)
        out[0] = (float)(red[0] / (double)((long long)B_N * F_N * T_N));
}

extern "C" void kernel_launch(void* const* d_in, const int* in_sizes, int n_in,
                              void* d_out, int out_size, void* d_ws, size_t ws_size,
                              hipStream_t stream) {
    const float* mo = (const float*)d_in[0];   // model_output (32,1025,2000) fp32
    const float* tg = (const float*)d_in[1];   // target       (32,1025,2000) fp32
    const float* M  = (const float*)d_in[2];   // transform_matrix (1025,1025) fp32
    float* out      = (float*)d_out;           // scalar fp32
    float* partials = (float*)d_ws;            // needs 16*13*32*4 = 26624 B of d_ws

    dim3 grid((T_N + TT - 1) / TT,             // 16 t-tiles
              (F_N + FC - 1) / FC,             // 13 f-chunks
              B_N);                            // 32 batches
    const int nparts = grid.x * grid.y * grid.z;

    mel_mse_main<<<grid, NT, 0, stream>>>(mo, tg, M, partials);
    mel_mse_reduce<<<1, 256, 0, stream>>>(partials, nparts, out);
}

// Round 2
// 131.025 us; speedup vs baseline: 2.1390x; 2.1390x over previous
//
#include <hip/hip_runtime.h>
#include <math.h>

// MelGaussianFilteredMSE:
//   diff = 10^(mo/10) - 10^(tg/10)            (B=32, F=1025, T=2000, fp32)
//   out  = mean( (M @ diff along F)^2 )       M is BANDED: half-width <= 10
//
// R1: streaming register rolling-window FIR (no data staging in LDS, no
// phase barrier). Each thread owns 2 t-columns and streams 126 F-rows
// (106 outputs + 20 halo; 126 = 6*21 so window slot indices are static
// after unrolling the 21-row macro-iteration). Coefficient band in LDS
// (uniform broadcast reads). Branch-free clamped+masked loads.

#define B_N 32
#define F_N 1025
#define T_N 2000

#define NOUT   106   // output rows per f-chunk; streamed rows = NOUT+20 = 126 = 6*21
#define NCHUNK 10    // ceil(1025/106)
#define NT     256   // threads per block
#define CT     512   // t-columns per block (256 threads * 2)
#define CST    24    // coeff LDS row stride (21 padded to 24, 96 B = 16B-aligned rows)

#define LOG2_10_DIV10 0.33219280948873623f   // 10^(x/10) = 2^(x*this)

__global__ __launch_bounds__(NT, 4)
void mel_mse_stream(const float* __restrict__ mo_g, const float* __restrict__ tg_g,
                    const float* __restrict__ M, float* __restrict__ partials) {
    __shared__ float sm[NOUT * CST];   // 106*24*4 = 10176 B
    __shared__ float red[NT];          //             1024 B

    const int tid = threadIdx.x;
    const int t0  = blockIdx.x * CT;
    const int f0  = blockIdx.y * NOUT;
    const int b   = blockIdx.z;
    const int t   = t0 + tid * 2;
    const bool active = (t + 1 < T_N);       // T_N even -> both cols valid or neither

    // ---- stage the 21-wide coefficient band for this chunk ----
    for (int i = tid; i < NOUT * 21; i += NT) {
        const int row = i / 21;
        const int j   = i - row * 21;
        const int f   = f0 + row;
        const int k   = f - 10 + j;
        float v = 0.f;
        if (f < F_N && k >= 0 && k < F_N) v = M[(size_t)f * F_N + k];
        sm[row * CST + j] = v;
    }
    __syncthreads();

    const int    tc      = active ? t : 0;
    const size_t colbase = ((size_t)b * F_N) * (size_t)T_N + tc;
    const int    base    = f0 - 10;          // global row of stream step 0

    float2 w[21];                            // rolling window, static-indexed only
    float  acc = 0.f;

    auto LOAD = [&](int r) -> float2 {
        int g = base + r;
        const float mask = (active && g >= 0 && g < F_N) ? 1.f : 0.f;
        g = g < 0 ? 0 : (g >= F_N ? F_N - 1 : g);
        const size_t off = colbase + (size_t)g * T_N;
        const float2 a = *reinterpret_cast<const float2*>(mo_g + off);
        const float2 c = *reinterpret_cast<const float2*>(tg_g + off);
        float2 d;
        d.x = (exp2f(a.x * LOG2_10_DIV10) - exp2f(c.x * LOG2_10_DIV10)) * mask;
        d.y = (exp2f(a.y * LOG2_10_DIV10) - exp2f(c.y * LOG2_10_DIV10)) * mask;
        return d;
    };
    // output row r_out (local); s0 = window slot holding tap 0 (compile-time)
    auto OUT = [&](int r_out, int s0) {
        if (f0 + r_out < F_N) {              // uniform runtime branch
            const float* c = &sm[r_out * CST];
            float2 o = make_float2(0.f, 0.f);
#pragma unroll
            for (int j = 0; j < 21; ++j) {
                const float  m  = c[j];
                const float2 wv = w[(s0 + j) % 21];
                o.x = fmaf(m, wv.x, o.x);
                o.y = fmaf(m, wv.y, o.y);
            }
            acc = fmaf(o.x, o.x, fmaf(o.y, o.y, acc));
        }
    };

    // ---- prologue: stream rows 0..20, emit output row 0 ----
#pragma unroll
    for (int i = 0; i < 21; ++i) w[i] = LOAD(i);
    OUT(0, 0);

    // ---- steady state: 5 macro-iterations of 21 rows ----
    for (int m = 1; m < 6; ++m) {
        const int rb = m * 21;
#pragma unroll
        for (int i = 0; i < 21; ++i) {
            w[i] = LOAD(rb + i);             // slot (rb+i)%21 == i
            OUT(rb + i - 20, (i + 1) % 21);  // tap j -> slot (i+1+j)%21, static
        }
    }

    // ---- block reduction ----
    red[tid] = acc;
    __syncthreads();
    for (int s = NT / 2; s > 0; s >>= 1) {
        if (tid < s) red[tid] += red[tid + s];
        __syncthreads();
    }
    if (tid == 0) {
        const int bid = blockIdx.x + gridDim.x * (blockIdx.y + gridDim.y * blockIdx.z);
        partials[bid] = red[0];
    }
}

__global__ void mel_mse_reduce(const float* __restrict__ partials, int n,
                               float* __restrict__ out) {
    __shared__ double red[256];
    double s = 0.0;
    for (int i = threadIdx.x; i < n; i += 256) s += (double)partials[i];
    red[threadIdx.x] = s;
    __syncthreads();
    for (int st = 128; st > 0; st >>= 1) {
        if (threadIdx.x < st) red[threadIdx.x] += red[threadIdx.x + st];
        __syncthreads();
    }
    if (threadIdx.x == 0)
        out[0] = (float)(red[0] / (double)((long long)B_N * F_N * T_N));
}

extern "C" void kernel_launch(void* const* d_in, const int* in_sizes, int n_in,
                              void* d_out, int out_size, void* d_ws, size_t ws_size,
                              hipStream_t stream) {
    const float* mo = (const float*)d_in[0];   // model_output (32,1025,2000) fp32
    const float* tg = (const float*)d_in[1];   // target       (32,1025,2000) fp32
    const float* M  = (const float*)d_in[2];   // transform_matrix (1025,1025) fp32
    float* out      = (float*)d_out;           // scalar fp32
    float* partials = (float*)d_ws;            // 4*10*32*4 = 5120 B of d_ws

    dim3 grid((T_N + CT - 1) / CT,             // 4 t-tiles
              NCHUNK,                          // 10 f-chunks
              B_N);                            // 32 batches
    const int nparts = grid.x * grid.y * grid.z;

    mel_mse_stream<<<grid, NT, 0, stream>>>(mo, tg, M, partials);
    mel_mse_reduce<<<1, 256, 0, stream>>>(partials, nparts, out);
}